// Round 1
// baseline (2226.142 us; speedup 1.0000x reference)
//
#include <hip/hip_runtime.h>
#include <hip/hip_bf16.h>

typedef __attribute__((ext_vector_type(4))) float f32x4;
typedef __attribute__((ext_vector_type(8))) short s16x8;
typedef __attribute__((ext_vector_type(4))) short s16x4;
typedef __attribute__((ext_vector_type(8))) unsigned short u16x8;
typedef __attribute__((ext_vector_type(4))) unsigned short u16x4;
typedef __attribute__((ext_vector_type(4))) float fv4;

#define DEV static __device__ __forceinline__

DEV unsigned short f2bf(float f) {
  union { float f; unsigned u; } v; v.f = f;
  return (unsigned short)((v.u + 0x7fffu + ((v.u >> 16) & 1u)) >> 16);
}
DEV float bf2f(unsigned short u) {
  union { unsigned u; float f; } v; v.u = ((unsigned)u) << 16; return v.f;
}

typedef const __attribute__((address_space(1))) void* gas_t;
typedef __attribute__((address_space(3))) void* las_t;
DEV void load_lds16(const void* g, void* l) {
  __builtin_amdgcn_global_load_lds((gas_t)g, (las_t)l, 16, 0, 0);
}

// ---------------- fp32 -> bf16 convert ----------------
__global__ __launch_bounds__(256) void cvt_kernel(const float* __restrict__ in,
                                                  unsigned short* __restrict__ out,
                                                  int n4) {
  int i = blockIdx.x * 256 + threadIdx.x;
  int stride = gridDim.x * 256;
  for (; i < n4; i += stride) {
    fv4 v = *(const fv4*)(in + (size_t)i * 4);
    u16x4 o;
    o[0] = f2bf(v[0]); o[1] = f2bf(v[1]); o[2] = f2bf(v[2]); o[3] = f2bf(v[3]);
    *(u16x4*)(out + (size_t)i * 4) = o;
  }
}

// ---------------- BT GEMM: C[m,n] = sum_k A[m,k]*B[n,k] ----------------
// EPI: 0 = plain bf16 out (ldc=N), 1 = +bias[n] then bf16, 2 = Vt mapping:
//   addr = (n>>9)*2^21 + m*512 + (n&511)   (per-batch transposed V)
template<int EPI>
__global__ __launch_bounds__(256) void gemm_bt(const unsigned short* __restrict__ A,
                                               const unsigned short* __restrict__ B,
                                               unsigned short* __restrict__ C,
                                               const float* __restrict__ bias,
                                               int M, int N, int K) {
  __shared__ unsigned short ldsA[128 * 32];
  __shared__ unsigned short ldsB[128 * 32];
  const int t = threadIdx.x;
  const int lane = t & 63;
  const int w = t >> 6;
  const int wr = w >> 1, wc = w & 1;
  const long brow = (long)blockIdx.y * 128;
  const long bcol = (long)blockIdx.x * 128;
  const int r0 = lane & 15;
  const int g8 = (lane >> 4) * 8;

  f32x4 acc[4][4] = {};

  const int srow = t >> 2;        // 0..63
  const int scol = (t & 3) * 8;   // element offset within 32-wide k tile
  const unsigned short* Ab = A + (brow + srow) * (long)K + scol;
  const unsigned short* Bb = B + (bcol + srow) * (long)K + scol;
  unsigned short* lA = ldsA + t * 8;
  unsigned short* lB = ldsB + t * 8;

  for (int kt = 0; kt < K; kt += 32) {
    load_lds16(Ab + kt, lA);
    load_lds16(Ab + 64 * (long)K + kt, lA + 2048);
    load_lds16(Bb + kt, lB);
    load_lds16(Bb + 64 * (long)K + kt, lB + 2048);
    __syncthreads();
    s16x8 av[4], bv[4];
#pragma unroll
    for (int mf = 0; mf < 4; ++mf)
      av[mf] = *(const s16x8*)&ldsA[(wr * 64 + mf * 16 + r0) * 32 + g8];
#pragma unroll
    for (int nf = 0; nf < 4; ++nf)
      bv[nf] = *(const s16x8*)&ldsB[(wc * 64 + nf * 16 + r0) * 32 + g8];
#pragma unroll
    for (int mf = 0; mf < 4; ++mf)
#pragma unroll
      for (int nf = 0; nf < 4; ++nf)
        acc[mf][nf] = __builtin_amdgcn_mfma_f32_16x16x32_bf16(av[mf], bv[nf], acc[mf][nf], 0, 0, 0);
    __syncthreads();
  }

  const int g4 = (lane >> 4) * 4;
#pragma unroll
  for (int mf = 0; mf < 4; ++mf) {
#pragma unroll
    for (int nf = 0; nf < 4; ++nf) {
      f32x4 v = acc[mf][nf];
      long col = bcol + wc * 64 + nf * 16 + r0;
#pragma unroll
      for (int r = 0; r < 4; ++r) {
        long row = brow + wr * 64 + mf * 16 + g4 + r;
        float val = v[r];
        if (EPI == 1) val += bias[col];
        if (EPI == 2) {
          long addr = ((col >> 9) << 21) + (row << 9) + (col & 511);
          C[addr] = f2bf(val);
        } else {
          C[row * (long)N + col] = f2bf(val);
        }
      }
    }
  }
}

// ---------------- fused attention ----------------
// grid: 1024 = B(16) * NH(16) * 4 q-tiles ; block: 512 (8 waves x 16 q-rows)
// S^T = K.Q^T via mfma(A=K, B=Q): lane owns q-row (lane&15), kcols in regs.
__global__ __launch_bounds__(512, 2) void attn_kernel(const unsigned short* __restrict__ Q,
                                                      const unsigned short* __restrict__ K,
                                                      const unsigned short* __restrict__ V,
                                                      const unsigned short* __restrict__ EP,
                                                      float* __restrict__ out) {
  __shared__ unsigned short lds[256 * 136]; // also used as [128][264]
  const int t = threadIdx.x;
  const int lane = t & 63;
  const int w = t >> 6;
  const int bid = blockIdx.x;
  const int qt = bid & 3;
  const int h = (bid >> 2) & 15;
  const int b = bid >> 6;
  const int r0 = lane & 15;
  const int g = lane >> 4;

  const int qrow = qt * 128 + w * 16;

  // Q fragments (B-operand): elem j = Q[q=r0][s*32 + g*8 + j]
  s16x8 qf[8];
  {
    const unsigned short* qp = Q + ((size_t)(b * 512 + qrow + r0)) * 4096 + h * 256 + g * 8;
#pragma unroll
    for (int s = 0; s < 8; ++s) qf[s] = *(const s16x8*)(qp + s * 32);
  }

  f32x4 st[32];
#pragma unroll
  for (int f = 0; f < 32; ++f) st[f] = f32x4{0.f, 0.f, 0.f, 0.f};

  // ---- Phase 1: S^T accumulation over 4 chunks of 128 kcols ----
#pragma unroll
  for (int kc = 0; kc < 4; ++kc) {
    {
      const unsigned short* kp = K + ((size_t)(b * 512 + kc * 128)) * 4096 + h * 256;
#pragma unroll
      for (int u = 0; u < 8; ++u) {
        int fidx = u * 4096 + t * 8;
        int row = fidx >> 8, c = fidx & 255;
        u16x8 v = *(const u16x8*)(kp + (size_t)row * 4096 + c);
        *(u16x8*)&lds[row * 264 + c] = v;
      }
    }
    __syncthreads();
#pragma unroll
    for (int mf = 0; mf < 8; ++mf) {
      const unsigned short* lk = &lds[(mf * 16 + r0) * 264 + g * 8];
#pragma unroll
      for (int s = 0; s < 8; ++s) {
        s16x8 af = *(const s16x8*)(lk + s * 32);
        st[kc * 8 + mf] = __builtin_amdgcn_mfma_f32_16x16x32_bf16(af, qf[s], st[kc * 8 + mf], 0, 0, 0);
      }
    }
    __syncthreads();
  }

  // ---- scale + EP bias add ----
  {
    const unsigned short* ep = EP + ((size_t)(b * 512 + qrow + r0)) * 8192 + h * 512 + g * 4;
#pragma unroll
    for (int f = 0; f < 32; ++f) {
      u16x4 e = *(const u16x4*)(ep + f * 16);
#pragma unroll
      for (int r = 0; r < 4; ++r)
        st[f][r] = st[f][r] * 0.0625f + bf2f(e[r]);
    }
  }

  // ---- softmax (row = lanes {r0, r0+16, r0+32, r0+48}) ----
  float mx = -1e30f;
#pragma unroll
  for (int f = 0; f < 32; ++f)
    mx = fmaxf(mx, fmaxf(fmaxf(st[f][0], st[f][1]), fmaxf(st[f][2], st[f][3])));
  mx = fmaxf(mx, __shfl_xor(mx, 16, 64));
  mx = fmaxf(mx, __shfl_xor(mx, 32, 64));
  float sum = 0.f;
#pragma unroll
  for (int f = 0; f < 32; ++f) {
#pragma unroll
    for (int r = 0; r < 4; ++r) {
      float e = __expf(st[f][r] - mx);
      st[f][r] = e;
      sum += e;
    }
  }
  sum += __shfl_xor(sum, 16, 64);
  sum += __shfl_xor(sum, 32, 64);
  const float rinv = 1.0f / sum;

  // P^T bf16 fragments: pair frags (2p, 2p+1) -> one K=32 B-operand
  s16x8 pb[16];
#pragma unroll
  for (int p = 0; p < 16; ++p) {
    s16x8 v;
#pragma unroll
    for (int j = 0; j < 4; ++j) {
      v[j] = (short)f2bf(st[2 * p][j] * rinv);
      v[j + 4] = (short)f2bf(st[2 * p + 1][j] * rinv);
    }
    pb[p] = v;
  }

  // ---- Phase 2: att^T = Vt . P^T ----
  f32x4 acc2[16];
#pragma unroll
  for (int d = 0; d < 16; ++d) acc2[d] = f32x4{0.f, 0.f, 0.f, 0.f};

#pragma unroll
  for (int kc = 0; kc < 4; ++kc) {
    {
      const unsigned short* vp = V + ((size_t)(b * 16 + h)) * 131072 + kc * 128;
#pragma unroll
      for (int u = 0; u < 8; ++u) {
        int fidx = u * 4096 + t * 8;
        int row = fidx >> 7, c = fidx & 127;
        u16x8 vv = *(const u16x8*)(vp + (size_t)row * 512 + c);
        *(u16x8*)&lds[row * 136 + c] = vv;
      }
    }
    __syncthreads();
#pragma unroll
    for (int d = 0; d < 16; ++d) {
      const unsigned short* lv = &lds[(d * 16 + r0) * 136 + g * 4];
#pragma unroll
      for (int p = 0; p < 4; ++p) {
        s16x4 a0 = *(const s16x4*)(lv + p * 32);
        s16x4 a1 = *(const s16x4*)(lv + p * 32 + 16);
        s16x8 av;
        av[0] = a0[0]; av[1] = a0[1]; av[2] = a0[2]; av[3] = a0[3];
        av[4] = a1[0]; av[5] = a1[1]; av[6] = a1[2]; av[7] = a1[3];
        acc2[d] = __builtin_amdgcn_mfma_f32_16x16x32_bf16(av, pb[kc * 4 + p], acc2[d], 0, 0, 0);
      }
    }
    __syncthreads();
  }

  // ---- write out: out[b, q, h*256 + d] fp32 ----
  {
    float* op = out + ((size_t)(b * 512 + qrow + r0)) * 4096 + h * 256 + g * 4;
#pragma unroll
    for (int d = 0; d < 16; ++d)
      *(fv4*)(op + d * 16) = acc2[d];
  }
}

// ---------------- host launch ----------------
extern "C" void kernel_launch(void* const* d_in, const int* in_sizes, int n_in,
                              void* d_out, int out_size, void* d_ws, size_t ws_size,
                              hipStream_t stream) {
  const float* x   = (const float*)d_in[0];
  const float* aug = (const float*)d_in[1];
  const float* wq  = (const float*)d_in[2];
  const float* wk  = (const float*)d_in[3];
  const float* wv  = (const float*)d_in[4];
  const float* wp  = (const float*)d_in[5];
  const float* bp  = (const float*)d_in[6];
  float* out = (float*)d_out;

  const size_t OFF_XA = 0;                       // 64 MiB: x_bf, later aug_bf
  const size_t OFF_WQ = 67108864;                // 32 MiB
  const size_t OFF_WK = OFF_WQ + 33554432;       // 32 MiB
  const size_t OFF_WV = OFF_WK + 33554432;       // 32 MiB (wp_bf overlays WQ+WK)
  const size_t OFF_Q  = OFF_WQ + 100663296;      // 64 MiB
  const size_t OFF_K  = OFF_Q + 67108864;        // 64 MiB
  const size_t OFF_VT = OFF_K + 67108864;        // 64 MiB
  const size_t OFF_EP = OFF_VT + 67108864;       // 128 MiB
  const size_t NEED   = OFF_EP + 134217728;      // 480 MiB total
  if (ws_size < NEED) return; // insufficient scratch: leave output untouched (visible as stub-failure)

  char* ws = (char*)d_ws;
  unsigned short* x_bf   = (unsigned short*)(ws + OFF_XA);
  unsigned short* aug_bf = (unsigned short*)(ws + OFF_XA);
  unsigned short* wq_bf  = (unsigned short*)(ws + OFF_WQ);
  unsigned short* wk_bf  = (unsigned short*)(ws + OFF_WK);
  unsigned short* wv_bf  = (unsigned short*)(ws + OFF_WV);
  unsigned short* wp_bf  = (unsigned short*)(ws + OFF_WQ);
  unsigned short* q_bf   = (unsigned short*)(ws + OFF_Q);
  unsigned short* k_bf   = (unsigned short*)(ws + OFF_K);
  unsigned short* vt_bf  = (unsigned short*)(ws + OFF_VT);
  unsigned short* ep_bf  = (unsigned short*)(ws + OFF_EP);

  // phase A: convert x + QKV weights
  cvt_kernel<<<2048, 256, 0, stream>>>(x, x_bf, 33554432 / 4);
  cvt_kernel<<<2048, 256, 0, stream>>>(wq, wq_bf, 16777216 / 4);
  cvt_kernel<<<2048, 256, 0, stream>>>(wk, wk_bf, 16777216 / 4);
  cvt_kernel<<<2048, 256, 0, stream>>>(wv, wv_bf, 16777216 / 4);

  // Q = x @ Wq^T ; K = x @ Wk^T   (M=8192, N=4096, K=4096)
  gemm_bt<0><<<dim3(32, 64), 256, 0, stream>>>(x_bf, wq_bf, q_bf, nullptr, 8192, 4096, 4096);
  gemm_bt<0><<<dim3(32, 64), 256, 0, stream>>>(x_bf, wk_bf, k_bf, nullptr, 8192, 4096, 4096);
  // Vt = Wv @ x^T  (M=4096 features, N=8192 tokens) -> (b, h, dk, n) layout
  gemm_bt<2><<<dim3(64, 32), 256, 0, stream>>>(wv_bf, x_bf, vt_bf, nullptr, 4096, 8192, 4096);

  // phase B: x_bf dead -> reuse for aug; wq/wk dead -> reuse for wp
  cvt_kernel<<<2048, 256, 0, stream>>>(aug, aug_bf, 33554432 / 4);
  cvt_kernel<<<2048, 256, 0, stream>>>(wp, wp_bf, 33554432 / 4);
  // EP = Aug @ Wp^T + bp  (M=8192, N=8192, K=4096)
  gemm_bt<1><<<dim3(64, 64), 256, 0, stream>>>(aug_bf, wp_bf, ep_bf, bp, 8192, 8192, 4096);

  // fused attention
  attn_kernel<<<1024, 512, 0, stream>>>(q_bf, k_bf, vt_bf, ep_bf, out);
}

// Round 2
// 1696.084 us; speedup vs baseline: 1.3125x; 1.3125x over previous
//
#include <hip/hip_runtime.h>
#include <hip/hip_bf16.h>

typedef __attribute__((ext_vector_type(4))) float f32x4;
typedef __attribute__((ext_vector_type(8))) short s16x8;
typedef __attribute__((ext_vector_type(4))) short s16x4;
typedef __attribute__((ext_vector_type(8))) unsigned short u16x8;
typedef __attribute__((ext_vector_type(4))) unsigned short u16x4;
typedef __attribute__((ext_vector_type(4))) float fv4;

#define DEV static __device__ __forceinline__

DEV unsigned short f2bf(float f) {
  union { float f; unsigned u; } v; v.f = f;
  return (unsigned short)((v.u + 0x7fffu + ((v.u >> 16) & 1u)) >> 16);
}
DEV float bf2f(unsigned short u) {
  union { unsigned u; float f; } v; v.u = ((unsigned)u) << 16; return v.f;
}

typedef const __attribute__((address_space(1))) void* gas_t;
typedef __attribute__((address_space(3))) void* las_t;
DEV void load_lds16(const void* g, void* l) {
  __builtin_amdgcn_global_load_lds((gas_t)g, (las_t)l, 16, 0, 0);
}

// ---------------- fp32 -> bf16 convert ----------------
__global__ __launch_bounds__(256) void cvt_kernel(const float* __restrict__ in,
                                                  unsigned short* __restrict__ out,
                                                  int n4) {
  int i = blockIdx.x * 256 + threadIdx.x;
  int stride = gridDim.x * 256;
  for (; i < n4; i += stride) {
    fv4 v = *(const fv4*)(in + (size_t)i * 4);
    u16x4 o;
    o[0] = f2bf(v[0]); o[1] = f2bf(v[1]); o[2] = f2bf(v[2]); o[3] = f2bf(v[3]);
    *(u16x4*)(out + (size_t)i * 4) = o;
  }
}

// ---------------- 256x256 BT GEMM, BK=32, ring-4 LDS, counted vmcnt ------
// C[m,n] = sum_k A[m,k]*B[n,k].  All dims multiples of 256 (K mult of 32).
// EPI: 0 = bf16 out (ldc=N), 1 = +bias[n] bf16, 2 = Vt mapping
//   addr = (n>>9)*2^21 + m*512 + (n&511)
// LDS swizzle (T2): within each [256][32] bf16 tile (64B rows),
//   byte' = byte ^ (((row>>1)&3)<<4)  -- involution, bits 4-5 only.
// Applied via pre-swizzled global source (global_load_lds writes linear)
// + swizzled ds_read address (both-sides rule, m201/m173).
template<int EPI>
__global__ __launch_bounds__(512, 2) void gemm256(const unsigned short* __restrict__ A,
                                                  const unsigned short* __restrict__ B,
                                                  unsigned short* __restrict__ C,
                                                  const float* __restrict__ bias,
                                                  int N, int K, int nbx_sh) {
  __shared__ unsigned short lds[4][2][8192]; // 4 bufs x (A,B) x 256x32 bf16 = 128 KiB
  const int t = threadIdx.x;
  const int lane = t & 63;
  const int w = t >> 6;
  const int wr = w >> 2;   // 0..1
  const int wc = w & 3;    // 0..3
  const int r0 = lane & 15;
  const int g = lane >> 4; // 0..3

  // T1: bijective XCD swizzle (gridDim.x % 8 == 0)
  const int nwg = gridDim.x;
  const int swz = (blockIdx.x & 7) * (nwg >> 3) + (blockIdx.x >> 3);
  const int by = swz >> nbx_sh;
  const int bx = swz & ((1 << nbx_sh) - 1);
  const long brow = (long)by * 256;
  const long bcol = (long)bx * 256;

  // staging: thread t loads 16B; LDS linear pos p = t*16 (+8192 for row+128)
  // row = p>>6, col16 = (t&3); source col pre-swizzled by ((t>>3)&3)
  const int srow = t >> 2;                            // 0..127
  const int scol = ((t & 3) ^ ((t >> 3) & 3)) * 8;    // elems
  const unsigned short* As = A + (brow + srow) * (long)K + scol;
  const unsigned short* Bs = B + (bcol + srow) * (long)K + scol;
  const int d0 = t * 8; // elems

#define STAGE(kt, bufi)                                                 \
  do {                                                                  \
    const long k0_ = (long)(kt) << 5;                                   \
    load_lds16(As + k0_,                 &lds[bufi][0][d0]);            \
    load_lds16(As + 128 * (long)K + k0_, &lds[bufi][0][d0 + 4096]);     \
    load_lds16(Bs + k0_,                 &lds[bufi][1][d0]);            \
    load_lds16(Bs + 128 * (long)K + k0_, &lds[bufi][1][d0 + 4096]);     \
  } while (0)

  f32x4 acc[8][4] = {};
  const int NT = K >> 5;

  // prologue: 3 tiles in flight, drain tile 0 (12 outstanding -> keep 8)
  STAGE(0, 0); STAGE(1, 1); STAGE(2, 2);
  asm volatile("s_waitcnt vmcnt(8)" ::: "memory");
  __builtin_amdgcn_s_barrier();
  __builtin_amdgcn_sched_barrier(0);

  // swizzled k-column offset: constant per lane ((row>>1)&3 == (r0>>1)&3)
  const int cswz = (g ^ ((r0 >> 1) & 3)) * 8; // elems
  const int arow = wr * 128 + r0;
  const int brw = wc * 64 + r0;

  for (int kt = 0; kt < NT; ++kt) {
    const unsigned short* lA = &lds[kt & 3][0][0];
    const unsigned short* lB = &lds[kt & 3][1][0];
    if (kt + 3 < NT) STAGE(kt + 3, (kt + 3) & 3);
    s16x8 av[8], bv[4];
#pragma unroll
    for (int m = 0; m < 8; ++m)
      av[m] = *(const s16x8*)&lA[(arow + m * 16) * 32 + cswz];
#pragma unroll
    for (int n = 0; n < 4; ++n)
      bv[n] = *(const s16x8*)&lB[(brw + n * 16) * 32 + cswz];
    __builtin_amdgcn_s_setprio(1);
#pragma unroll
    for (int m = 0; m < 8; ++m)
#pragma unroll
      for (int n = 0; n < 4; ++n)
        acc[m][n] = __builtin_amdgcn_mfma_f32_16x16x32_bf16(av[m], bv[n], acc[m][n], 0, 0, 0);
    __builtin_amdgcn_s_setprio(0);
    // boundary: tile kt+1 must be drained; tiles kt+2, kt+3 may stay in flight
    const int rem = NT - 1 - kt;
    if (rem >= 3)      asm volatile("s_waitcnt vmcnt(8)" ::: "memory");
    else if (rem == 2) asm volatile("s_waitcnt vmcnt(4)" ::: "memory");
    else if (rem == 1) asm volatile("s_waitcnt vmcnt(0)" ::: "memory");
    __builtin_amdgcn_s_barrier();
    __builtin_amdgcn_sched_barrier(0);
  }
#undef STAGE

  const int g4 = g * 4;
#pragma unroll
  for (int m = 0; m < 8; ++m) {
#pragma unroll
    for (int n = 0; n < 4; ++n) {
      f32x4 v = acc[m][n];
      long col = bcol + wc * 64 + n * 16 + r0;
#pragma unroll
      for (int r = 0; r < 4; ++r) {
        long row = brow + wr * 128 + m * 16 + g4 + r;
        float val = v[r];
        if (EPI == 1) val += bias[col];
        if (EPI == 2) {
          long addr = ((col >> 9) << 21) + (row << 9) + (col & 511);
          C[addr] = f2bf(val);
        } else {
          C[row * (long)N + col] = f2bf(val);
        }
      }
    }
  }
}

// ---------------- fused attention ----------------
// grid: 1024 = B(16) * NH(16) * 4 q-tiles ; block: 512 (8 waves x 16 q-rows)
__global__ __launch_bounds__(512, 2) void attn_kernel(const unsigned short* __restrict__ Q,
                                                      const unsigned short* __restrict__ K,
                                                      const unsigned short* __restrict__ V,
                                                      const unsigned short* __restrict__ EP,
                                                      float* __restrict__ out) {
  __shared__ unsigned short lds[256 * 136]; // also used as [128][264]
  const int t = threadIdx.x;
  const int lane = t & 63;
  const int w = t >> 6;
  const int bid = blockIdx.x;
  const int qt = bid & 3;
  const int h = (bid >> 2) & 15;
  const int b = bid >> 6;
  const int r0 = lane & 15;
  const int g = lane >> 4;

  const int qrow = qt * 128 + w * 16;

  s16x8 qf[8];
  {
    const unsigned short* qp = Q + ((size_t)(b * 512 + qrow + r0)) * 4096 + h * 256 + g * 8;
#pragma unroll
    for (int s = 0; s < 8; ++s) qf[s] = *(const s16x8*)(qp + s * 32);
  }

  f32x4 st[32];
#pragma unroll
  for (int f = 0; f < 32; ++f) st[f] = f32x4{0.f, 0.f, 0.f, 0.f};

#pragma unroll
  for (int kc = 0; kc < 4; ++kc) {
    {
      const unsigned short* kp = K + ((size_t)(b * 512 + kc * 128)) * 4096 + h * 256;
#pragma unroll
      for (int u = 0; u < 8; ++u) {
        int fidx = u * 4096 + t * 8;
        int row = fidx >> 8, c = fidx & 255;
        u16x8 v = *(const u16x8*)(kp + (size_t)row * 4096 + c);
        *(u16x8*)&lds[row * 264 + c] = v;
      }
    }
    __syncthreads();
#pragma unroll
    for (int mf = 0; mf < 8; ++mf) {
      const unsigned short* lk = &lds[(mf * 16 + r0) * 264 + g * 8];
#pragma unroll
      for (int s = 0; s < 8; ++s) {
        s16x8 af = *(const s16x8*)(lk + s * 32);
        st[kc * 8 + mf] = __builtin_amdgcn_mfma_f32_16x16x32_bf16(af, qf[s], st[kc * 8 + mf], 0, 0, 0);
      }
    }
    __syncthreads();
  }

  {
    const unsigned short* ep = EP + ((size_t)(b * 512 + qrow + r0)) * 8192 + h * 512 + g * 4;
#pragma unroll
    for (int f = 0; f < 32; ++f) {
      u16x4 e = *(const u16x4*)(ep + f * 16);
#pragma unroll
      for (int r = 0; r < 4; ++r)
        st[f][r] = st[f][r] * 0.0625f + bf2f(e[r]);
    }
  }

  float mx = -1e30f;
#pragma unroll
  for (int f = 0; f < 32; ++f)
    mx = fmaxf(mx, fmaxf(fmaxf(st[f][0], st[f][1]), fmaxf(st[f][2], st[f][3])));
  mx = fmaxf(mx, __shfl_xor(mx, 16, 64));
  mx = fmaxf(mx, __shfl_xor(mx, 32, 64));
  float sum = 0.f;
#pragma unroll
  for (int f = 0; f < 32; ++f) {
#pragma unroll
    for (int r = 0; r < 4; ++r) {
      float e = __expf(st[f][r] - mx);
      st[f][r] = e;
      sum += e;
    }
  }
  sum += __shfl_xor(sum, 16, 64);
  sum += __shfl_xor(sum, 32, 64);
  const float rinv = 1.0f / sum;

  s16x8 pb[16];
#pragma unroll
  for (int p = 0; p < 16; ++p) {
    s16x8 v;
#pragma unroll
    for (int j = 0; j < 4; ++j) {
      v[j] = (short)f2bf(st[2 * p][j] * rinv);
      v[j + 4] = (short)f2bf(st[2 * p + 1][j] * rinv);
    }
    pb[p] = v;
  }

  f32x4 acc2[16];
#pragma unroll
  for (int d = 0; d < 16; ++d) acc2[d] = f32x4{0.f, 0.f, 0.f, 0.f};

#pragma unroll
  for (int kc = 0; kc < 4; ++kc) {
    {
      const unsigned short* vp = V + ((size_t)(b * 16 + h)) * 131072 + kc * 128;
#pragma unroll
      for (int u = 0; u < 8; ++u) {
        int fidx = u * 4096 + t * 8;
        int row = fidx >> 7, c = fidx & 127;
        u16x8 vv = *(const u16x8*)(vp + (size_t)row * 512 + c);
        *(u16x8*)&lds[row * 136 + c] = vv;
      }
    }
    __syncthreads();
#pragma unroll
    for (int d = 0; d < 16; ++d) {
      const unsigned short* lv = &lds[(d * 16 + r0) * 136 + g * 4];
#pragma unroll
      for (int p = 0; p < 4; ++p) {
        s16x4 a0 = *(const s16x4*)(lv + p * 32);
        s16x4 a1 = *(const s16x4*)(lv + p * 32 + 16);
        s16x8 av;
        av[0] = a0[0]; av[1] = a0[1]; av[2] = a0[2]; av[3] = a0[3];
        av[4] = a1[0]; av[5] = a1[1]; av[6] = a1[2]; av[7] = a1[3];
        acc2[d] = __builtin_amdgcn_mfma_f32_16x16x32_bf16(av, pb[kc * 4 + p], acc2[d], 0, 0, 0);
      }
    }
    __syncthreads();
  }

  {
    float* op = out + ((size_t)(b * 512 + qrow + r0)) * 4096 + h * 256 + g * 4;
#pragma unroll
    for (int d = 0; d < 16; ++d)
      *(fv4*)(op + d * 16) = acc2[d];
  }
}

// ---------------- host launch ----------------
extern "C" void kernel_launch(void* const* d_in, const int* in_sizes, int n_in,
                              void* d_out, int out_size, void* d_ws, size_t ws_size,
                              hipStream_t stream) {
  const float* x   = (const float*)d_in[0];
  const float* aug = (const float*)d_in[1];
  const float* wq  = (const float*)d_in[2];
  const float* wk  = (const float*)d_in[3];
  const float* wv  = (const float*)d_in[4];
  const float* wp  = (const float*)d_in[5];
  const float* bp  = (const float*)d_in[6];
  float* out = (float*)d_out;

  const size_t OFF_XA = 0;                       // 64 MiB: x_bf, later aug_bf
  const size_t OFF_WQ = 67108864;                // 32 MiB
  const size_t OFF_WK = OFF_WQ + 33554432;       // 32 MiB
  const size_t OFF_WV = OFF_WK + 33554432;       // 32 MiB (wp_bf overlays WQ+WK)
  const size_t OFF_Q  = OFF_WQ + 100663296;      // 64 MiB
  const size_t OFF_K  = OFF_Q + 67108864;        // 64 MiB
  const size_t OFF_VT = OFF_K + 67108864;        // 64 MiB
  const size_t OFF_EP = OFF_VT + 67108864;       // 128 MiB
  const size_t NEED   = OFF_EP + 134217728;      // 480 MiB total
  if (ws_size < NEED) return;

  char* ws = (char*)d_ws;
  unsigned short* x_bf   = (unsigned short*)(ws + OFF_XA);
  unsigned short* aug_bf = (unsigned short*)(ws + OFF_XA);
  unsigned short* wq_bf  = (unsigned short*)(ws + OFF_WQ);
  unsigned short* wk_bf  = (unsigned short*)(ws + OFF_WK);
  unsigned short* wv_bf  = (unsigned short*)(ws + OFF_WV);
  unsigned short* wp_bf  = (unsigned short*)(ws + OFF_WQ);
  unsigned short* q_bf   = (unsigned short*)(ws + OFF_Q);
  unsigned short* k_bf   = (unsigned short*)(ws + OFF_K);
  unsigned short* vt_bf  = (unsigned short*)(ws + OFF_VT);
  unsigned short* ep_bf  = (unsigned short*)(ws + OFF_EP);

  // phase A: convert x + QKV weights
  cvt_kernel<<<2048, 256, 0, stream>>>(x, x_bf, 33554432 / 4);
  cvt_kernel<<<2048, 256, 0, stream>>>(wq, wq_bf, 16777216 / 4);
  cvt_kernel<<<2048, 256, 0, stream>>>(wk, wk_bf, 16777216 / 4);
  cvt_kernel<<<2048, 256, 0, stream>>>(wv, wv_bf, 16777216 / 4);

  // Q = x @ Wq^T ; K = x @ Wk^T   (M=8192, N=4096) grid 32x16=512
  gemm256<0><<<512, 512, 0, stream>>>(x_bf, wq_bf, q_bf, nullptr, 4096, 4096, 4);
  gemm256<0><<<512, 512, 0, stream>>>(x_bf, wk_bf, k_bf, nullptr, 4096, 4096, 4);
  // Vt = Wv @ x^T  (M=4096, N=8192) grid 16x32=512
  gemm256<2><<<512, 512, 0, stream>>>(wv_bf, x_bf, vt_bf, nullptr, 8192, 4096, 5);

  // phase B: x_bf dead -> reuse for aug; wq/wk dead -> reuse for wp
  cvt_kernel<<<2048, 256, 0, stream>>>(aug, aug_bf, 33554432 / 4);
  cvt_kernel<<<2048, 256, 0, stream>>>(wp, wp_bf, 33554432 / 4);
  // EP = Aug @ Wp^T + bp  (M=8192, N=8192) grid 32x32=1024
  gemm256<1><<<1024, 512, 0, stream>>>(aug_bf, wp_bf, ep_bf, bp, 8192, 4096, 5);

  // fused attention
  attn_kernel<<<1024, 512, 0, stream>>>(q_bf, k_bf, vt_bf, ep_bf, out);
}